// Round 13
// baseline (263.273 us; speedup 1.0000x reference)
//
#include <hip/hip_runtime.h>

// ---------------------------------------------------------------------------
// RestaurantGNN: AGNNConv -> TransformerEncoderLayer (post-LN) -> fc -> head
// N=8192, D=128, NH=2, HD=64, DFF=2048, H=256, E=262144
// Round 13: k_attn K/V double-buffered — loads for iter kt+1 issued into
// buf^1 BEFORE computing on buf (so the barrier's vmcnt(0) drain finds them
// already complete). LDS 68.9KB, still 2 blocks/CU; launch_bounds(256,2)
// keeps the proven 112-VGPR no-spill allocation. Rest identical to R12.
// ---------------------------------------------------------------------------

typedef __attribute__((ext_vector_type(4))) float  f32x4;
typedef __attribute__((ext_vector_type(8))) __bf16 bf16x8;

#define DEV __device__ __forceinline__

DEV unsigned short f2bf_bits(float f) {       // RNE fp32 -> bf16 bits
  union { float f; unsigned u; } v; v.f = f;
  unsigned r = v.u + 0x7FFFu + ((v.u >> 16) & 1u);
  return (unsigned short)(r >> 16);
}

DEV __bf16 f2bf(float f) {
  union { unsigned short s; __bf16 b; } o; o.s = f2bf_bits(f);
  return o.b;
}

DEV f32x4 mfma16(bf16x8 a, bf16x8 b, f32x4 c) {
  return __builtin_amdgcn_mfma_f32_16x16x32_bf16(a, b, c, 0, 0, 0);
}

DEV bf16x8 ones8() {                          // bf16 1.0 x8
  union { unsigned short s[8]; bf16x8 v; } u;
#pragma unroll
  for (int i = 0; i < 8; i++) u.s[i] = 0x3F80;
  return u.v;
}

DEV void ub8(bf16x8 v, float* f) {            // unpack 8 bf16 -> fp32
  union { bf16x8 v; unsigned short s[8]; } u; u.v = v;
#pragma unroll
  for (int i = 0; i < 8; i++) {
    union { unsigned u; float f; } w; w.u = (unsigned)u.s[i] << 16;
    f[i] = w.f;
  }
}

// async global->LDS, 16B/lane; LDS dest = wave-uniform base + lane*16
#define GLD16(gp, lp) __builtin_amdgcn_global_load_lds(                        \
    (const __attribute__((address_space(1))) void*)(gp),                       \
    (__attribute__((address_space(3))) void*)(lp), 16, 0, 0)

// --------------------- prep: norm + counts-zero + weight cvt ---------------

__global__ __launch_bounds__(256) void k_prep(
    const float* __restrict__ x, float* __restrict__ inv,
    int* __restrict__ counts, const float* __restrict__ s0,
    const float* __restrict__ s1, const float* __restrict__ s2,
    const float* __restrict__ s3, const float* __restrict__ s4, __bf16* d0,
    __bf16* d1, __bf16* d2, __bf16* d3, __bf16* d4) {
  const int n0 = 384 * 128, n1 = 128 * 128, n2 = 2048 * 128, n3 = 128 * 2048,
            n4 = 256 * 128;
  if (blockIdx.x < 2048) {
    int lane = threadIdx.x & 63, w = threadIdx.x >> 6;
    int row = blockIdx.x * 4 + w;
    float2 v = ((const float2*)(x + (size_t)row * 128))[lane];
    float s = v.x * v.x + v.y * v.y;
#pragma unroll
    for (int m = 1; m < 64; m <<= 1) s += __shfl_xor(s, m);
    if (lane == 0) {
      inv[row] = 1.f / fmaxf(sqrtf(s), 1e-12f);
      counts[row] = 0;
    }
    return;
  }
  int t = (blockIdx.x - 2048) * 256 + threadIdx.x;
  if (t < n0) { d0[t] = f2bf(s0[t]); return; } t -= n0;
  if (t < n1) { d1[t] = f2bf(s1[t]); return; } t -= n1;
  if (t < n2) { d2[t] = f2bf(s2[t]); return; } t -= n2;
  if (t < n3) { d3[t] = f2bf(s3[t]); return; } t -= n3;
  if (t < n4) { d4[t] = f2bf(s4[t]); }
}

// ------------------------------ CSR build ----------------------------------

__global__ void k_count(const int* __restrict__ ei, int* __restrict__ counts,
                        int E) {
  int e = blockIdx.x * 256 + threadIdx.x;
  if (e < E) atomicAdd(&counts[ei[E + e]], 1);
}

__global__ __launch_bounds__(256) void k_scan(const int* __restrict__ counts,
                                              int* __restrict__ offs,
                                              int* __restrict__ cursor) {
  __shared__ int sums[256];
  int t = threadIdx.x, base = t * 32;
  int s = 0;
  for (int i = 0; i < 32; i++) s += counts[base + i];
  sums[t] = s;
  __syncthreads();
  for (int off = 1; off < 256; off <<= 1) {
    int v = (t >= off) ? sums[t - off] : 0;
    __syncthreads();
    sums[t] += v;
    __syncthreads();
  }
  int run = sums[t] - s;  // exclusive prefix
  for (int i = 0; i < 32; i++) {
    offs[base + i] = run; cursor[base + i] = run;
    run += counts[base + i];
  }
  if (t == 255) offs[8192] = run;
}

__global__ void k_scatter(const int* __restrict__ ei, int* __restrict__ cursor,
                          int* __restrict__ csr, int E) {
  int e = blockIdx.x * 256 + threadIdx.x;
  if (e < E) {
    int dst = ei[E + e];
    int pos = atomicAdd(&cursor[dst], 1);
    csr[pos] = ei[e];
  }
}

// AGNN aggregate: wave per destination node, 2-edge unroll for latency ILP.
__global__ __launch_bounds__(256) void k_agnn(
    const float* __restrict__ x, const int* __restrict__ csr,
    const int* __restrict__ offs, const float* __restrict__ inv,
    const float* __restrict__ betap, float* __restrict__ hf,
    __bf16* __restrict__ hb) {
  int lane = threadIdx.x & 63, w = threadIdx.x >> 6;
  int dst = blockIdx.x * 4 + w;
  float beta = *betap;
  float2 xd = ((const float2*)(x + (size_t)dst * 128))[lane];
  float invd = inv[dst];
  float sd = xd.x * xd.x + xd.y * xd.y;
#pragma unroll
  for (int m = 1; m < 64; m <<= 1) sd += __shfl_xor(sd, m);
  float z = __expf(beta * sd * invd * invd);  // self-loop (cos==1)
  float ax = z * xd.x, ay = z * xd.y;
  int e0 = offs[dst], e1 = offs[dst + 1];
  int e = e0;
  for (; e + 2 <= e1; e += 2) {
    int s0 = csr[e], s1 = csr[e + 1];
    float2 xa = ((const float2*)(x + (size_t)s0 * 128))[lane];
    float2 xb = ((const float2*)(x + (size_t)s1 * 128))[lane];
    float ia = inv[s0], ib = inv[s1];
    float da = xd.x * xa.x + xd.y * xa.y;
    float db = xd.x * xb.x + xd.y * xb.y;
#pragma unroll
    for (int m = 1; m < 64; m <<= 1) {
      da += __shfl_xor(da, m);
      db += __shfl_xor(db, m);
    }
    float sa = __expf(beta * da * invd * ia);
    float sb = __expf(beta * db * invd * ib);
    z += sa + sb;
    ax += sa * xa.x + sb * xb.x;
    ay += sa * xa.y + sb * xb.y;
  }
  if (e < e1) {
    int s0 = csr[e];
    float2 xa = ((const float2*)(x + (size_t)s0 * 128))[lane];
    float da = xd.x * xa.x + xd.y * xa.y;
#pragma unroll
    for (int m = 1; m < 64; m <<= 1) da += __shfl_xor(da, m);
    float sa = __expf(beta * da * invd * inv[s0]);
    z += sa; ax += sa * xa.x; ay += sa * xa.y;
  }
  float r = 1.f / z;
  ax *= r; ay *= r;
  float2 o; o.x = ax; o.y = ay;
  ((float2*)(hf + (size_t)dst * 128))[lane] = o;
  hb[(size_t)dst * 128 + 2 * lane]     = f2bf(ax);
  hb[(size_t)dst * 128 + 2 * lane + 1] = f2bf(ay);
}

// ------------------------------- GEMM --------------------------------------
__global__ __launch_bounds__(256, 3) void k_gemm(
    const __bf16* __restrict__ A, const __bf16* __restrict__ B,
    const float* __restrict__ bias, float* __restrict__ Cf,
    __bf16* __restrict__ Cb, float* __restrict__ Cpart, int M, int N, int K,
    int relu) {
  __shared__ __bf16 As[128 * 64];
  __shared__ __bf16 Bs[128 * 64];
  const int tid = threadIdx.x, lane = tid & 63, wid = tid >> 6;
  const int wm = wid & 1, wn = wid >> 1;
  const int bm = blockIdx.x * 128, bn = blockIdx.y * 128;
  const int kz = blockIdx.z, nkz = gridDim.z;
  const int kchunk = K / nkz, k0beg = kz * kchunk, k0end = k0beg + kchunk;
  const int lr = lane >> 3, lc8 = (lane & 7) * 8;
  const int l15 = lane & 15, quad = lane >> 4, kq = quad * 8;

  f32x4 acc[4][4] = {};
  const __bf16* Ab = A + (size_t)(bm + lr) * K + lc8;
  const __bf16* Bb = B + (size_t)(bn + lr) * K + lc8;

  for (int k0 = k0beg; k0 < k0end; k0 += 64) {
#pragma unroll
    for (int i = 0; i < 4; i++) {
      int j = wid * 4 + i;
      GLD16(Ab + (size_t)(8 * j) * K + k0, &As[j * 512]);
      GLD16(Bb + (size_t)(8 * j) * K + k0, &Bs[j * 512]);
    }
    __syncthreads();
    const int ar = (wm * 64 + l15) * 64 + kq;
    const int br = (wn * 64 + l15) * 64 + kq;
#pragma unroll
    for (int kk = 0; kk < 2; kk++) {
      bf16x8 a[4], b[4];
#pragma unroll
      for (int mt = 0; mt < 4; mt++)
        a[mt] = *(const bf16x8*)&As[ar + mt * 1024 + kk * 32];
#pragma unroll
      for (int nt = 0; nt < 4; nt++)
        b[nt] = *(const bf16x8*)&Bs[br + nt * 1024 + kk * 32];
#pragma unroll
      for (int mt = 0; mt < 4; mt++)
#pragma unroll
        for (int nt = 0; nt < 4; nt++)
          acc[mt][nt] = mfma16(a[mt], b[nt], acc[mt][nt]);
    }
    __syncthreads();
  }
  const int col0 = bn + wn * 64 + l15;
  const int row0 = bm + wm * 64 + quad * 4;
  if (Cpart) {
    float* P = Cpart + (size_t)kz * M * N;
#pragma unroll
    for (int mt = 0; mt < 4; mt++)
#pragma unroll
      for (int nt = 0; nt < 4; nt++)
#pragma unroll
        for (int r = 0; r < 4; r++)
          P[(size_t)(row0 + mt * 16 + r) * N + col0 + nt * 16] = acc[mt][nt][r];
  } else {
#pragma unroll
    for (int nt = 0; nt < 4; nt++) {
      float bv = bias[col0 + nt * 16];
#pragma unroll
      for (int mt = 0; mt < 4; mt++)
#pragma unroll
        for (int r = 0; r < 4; r++) {
          float v = acc[mt][nt][r] + bv;
          if (relu) v = fmaxf(v, 0.f);
          size_t idx = (size_t)(row0 + mt * 16 + r) * N + col0 + nt * 16;
          if (Cf) Cf[idx] = v;
          if (Cb) Cb[idx] = f2bf(v);
        }
    }
  }
}

// ------------------- qkv GEMM with fused Q/K/V epilogue --------------------
__global__ __launch_bounds__(256, 2) void k_gemm_qkv(
    const __bf16* __restrict__ A, const __bf16* __restrict__ B,
    const float* __restrict__ bias, __bf16* __restrict__ Qb,
    __bf16* __restrict__ Kb, __bf16* __restrict__ Vtb) {
  __shared__ __bf16 smem[17408];  // staging 2x8192 | transpose tile 128x136
  __bf16* As = smem;
  __bf16* Bs = smem + 8192;
  const int K = 128;
  const int tid = threadIdx.x, lane = tid & 63, wid = tid >> 6;
  const int wm = wid & 1, wn = wid >> 1;
  const int bm = blockIdx.x * 128, y = blockIdx.y, bn = y * 128;
  const int lr = lane >> 3, lc8 = (lane & 7) * 8;
  const int l15 = lane & 15, quad = lane >> 4, kq = quad * 8;
  const float qscale = 0.125f * 1.44269504089f;

  f32x4 acc[4][4] = {};
  const __bf16* Ab = A + (size_t)(bm + lr) * K + lc8;
  const __bf16* Bb = B + (size_t)(bn + lr) * K + lc8;

  for (int k0 = 0; k0 < 128; k0 += 64) {
#pragma unroll
    for (int i = 0; i < 4; i++) {
      int j = wid * 4 + i;
      GLD16(Ab + (size_t)(8 * j) * K + k0, &As[j * 512]);
      GLD16(Bb + (size_t)(8 * j) * K + k0, &Bs[j * 512]);
    }
    __syncthreads();
    const int ar = (wm * 64 + l15) * 64 + kq;
    const int br = (wn * 64 + l15) * 64 + kq;
#pragma unroll
    for (int kk = 0; kk < 2; kk++) {
      bf16x8 a[4], b[4];
#pragma unroll
      for (int mt = 0; mt < 4; mt++)
        a[mt] = *(const bf16x8*)&As[ar + mt * 1024 + kk * 32];
#pragma unroll
      for (int nt = 0; nt < 4; nt++)
        b[nt] = *(const bf16x8*)&Bs[br + nt * 1024 + kk * 32];
#pragma unroll
      for (int mt = 0; mt < 4; mt++)
#pragma unroll
        for (int nt = 0; nt < 4; nt++)
          acc[mt][nt] = mfma16(a[mt], b[nt], acc[mt][nt]);
    }
    __syncthreads();
  }

  if (y < 2) {
    __bf16* D = (y == 0) ? Qb : Kb;
    float sc = (y == 0) ? qscale : 1.f;
    int h = wn;
#pragma unroll
    for (int nt = 0; nt < 4; nt++) {
      int c = wn * 64 + nt * 16 + l15;
      float bv = bias[bn + c];
      int d = nt * 16 + l15;
#pragma unroll
      for (int mt = 0; mt < 4; mt++)
#pragma unroll
        for (int r = 0; r < 4; r++) {
          int row = bm + wm * 64 + mt * 16 + quad * 4 + r;
          D[(size_t)h * 524288 + (size_t)row * 64 + d] =
              f2bf((acc[mt][nt][r] + bv) * sc);
        }
    }
  } else {
#pragma unroll
    for (int nt = 0; nt < 4; nt++) {
      int c = wn * 64 + nt * 16 + l15;
      float bv = bias[bn + c];
#pragma unroll
      for (int mt = 0; mt < 4; mt++)
#pragma unroll
        for (int r = 0; r < 4; r++) {
          int nl = wm * 64 + mt * 16 + quad * 4 + r;
          smem[nl * 136 + c] = f2bf(acc[mt][nt][r] + bv);
        }
    }
    __syncthreads();
    int d = tid >> 1, nh = tid & 1;
    __bf16* dst = Vtb + (size_t)d * 8192 + bm + nh * 64;
#pragma unroll
    for (int i = 0; i < 8; i++) {
      union { unsigned short s[8]; bf16x8 v; } u;
#pragma unroll
      for (int e = 0; e < 8; e++)
        u.s[e] = *(const unsigned short*)&smem[(nh * 64 + i * 8 + e) * 136 + d];
      *(bf16x8*)(dst + i * 8) = u.v;
    }
  }
}

// ------------------------- flash attention ---------------------------------
// 256 thr (4 waves); wave = 64 q (4 subtiles) -> 256 q/block; K-split=8.
// K/V double-buffered: loads for kt+1 issued before computing kt, so the
// barrier's vmcnt(0) drain finds them complete. Ps stride 72; bounds(256,2)
// (proven 112-VGPR no-spill point). LDS 68.9KB -> 2 blocks/CU.
__global__ __launch_bounds__(256, 2) void k_attn(
    const __bf16* __restrict__ Qb, const __bf16* __restrict__ Kb,
    const __bf16* __restrict__ Vtb, __bf16* __restrict__ Opart,
    float* __restrict__ Lpart) {
  __shared__ __bf16 Ks[2][4096];     // [buf][4 frag x 2 khalf x 512]
  __shared__ __bf16 Vs[2][4096];
  __shared__ __bf16 Ps[4][64 * 72];  // per-wave P [q_local 64][k], stride 72

  const int tid = threadIdx.x, lane = tid & 63, w = tid >> 6;
  const int qt = blockIdx.x, h = blockIdx.y, kz = blockIdx.z;
  const int qbase = qt * 256;
  const int l15 = lane & 15, quad = lane >> 4;
  const int lofs = lane * 8;

  const __bf16* Qg = Qb + ((size_t)h * 8192 + qbase) * 64;
  const __bf16* Kg = Kb + (size_t)h * 8192 * 64;
  const __bf16* Vg = Vtb + (size_t)h * 64 * 8192;
  const bf16x8 vone = ones8();

  // stage Q (256 q x 64 d = 32KB) fragment-major into the Ps region
  __bf16* Qstage = &Ps[0][0];
#pragma unroll
  for (int i = 0; i < 4; i++) {
    int j = w * 4 + i;  // 16 frags of 16 q-rows
#pragma unroll
    for (int hh = 0; hh < 2; hh++)
      GLD16(Qg + (size_t)(j * 16 + l15) * 64 + hh * 32 + quad * 8,
            Qstage + j * 1024 + hh * 512);
  }
  __syncthreads();
  bf16x8 aq[4][2];
#pragma unroll
  for (int s = 0; s < 4; s++) {
    const __bf16* base = Qstage + (size_t)(w * 4 + s) * 1024;
    aq[s][0] = *(const bf16x8*)&base[lofs];
    aq[s][1] = *(const bf16x8*)&base[512 + lofs];
  }
  __syncthreads();

  f32x4 o[4][4] = {};
  f32x4 lacc[4] = {};
  const int kstart = kz * 1024;

  // prologue: stage kt=0 into buf 0 (wave w -> K-frag w, V-frag w)
#pragma unroll
  for (int hh = 0; hh < 2; hh++) {
    GLD16(Kg + (size_t)(kstart + w * 16 + l15) * 64 + hh * 32 + quad * 8,
          &Ks[0][w * 1024 + hh * 512]);
    GLD16(Vg + (size_t)(w * 16 + l15) * 8192 + kstart + hh * 32 + quad * 8,
          &Vs[0][w * 1024 + hh * 512]);
  }

  for (int kt = 0; kt < 16; kt++) {
    const int cur = kt & 1;
    __syncthreads();  // buf[cur] loads complete; buf[cur^1] readers done
    if (kt + 1 < 16) {
      int kb2 = kstart + (kt + 1) * 64;
#pragma unroll
      for (int hh = 0; hh < 2; hh++) {
        GLD16(Kg + (size_t)(kb2 + w * 16 + l15) * 64 + hh * 32 + quad * 8,
              &Ks[cur ^ 1][w * 1024 + hh * 512]);
        GLD16(Vg + (size_t)(w * 16 + l15) * 8192 + kb2 + hh * 32 + quad * 8,
              &Vs[cur ^ 1][w * 1024 + hh * 512]);
      }
    }

    // S^T = K x Q^T ; lane -> (k = mt*16+quad*4+r, q = s*16+l15)
#pragma unroll
    for (int mt = 0; mt < 4; mt++) {
      bf16x8 k0 = *(const bf16x8*)&Ks[cur][mt * 1024 + lofs];
      bf16x8 k1 = *(const bf16x8*)&Ks[cur][mt * 1024 + 512 + lofs];
#pragma unroll
      for (int s = 0; s < 4; s++) {
        f32x4 St = {};
        St = mfma16(k0, aq[s][0], St);
        St = mfma16(k1, aq[s][1], St);
        union { float f; unsigned u; } p0, p1, p2, p3;
        p0.f = __builtin_amdgcn_exp2f(St[0]);
        p1.f = __builtin_amdgcn_exp2f(St[1]);
        p2.f = __builtin_amdgcn_exp2f(St[2]);
        p3.f = __builtin_amdgcn_exp2f(St[3]);
        uint2 pk;
        pk.x = (p0.u >> 16) | (p1.u & 0xFFFF0000u);
        pk.y = (p2.u >> 16) | (p3.u & 0xFFFF0000u);
        *(uint2*)&Ps[w][(s * 16 + l15) * 72 + mt * 16 + quad * 4] = pk;
      }
    }
    // O += P x V ; L += P x ones   (V frags shared by all 4 subtiles)
    bf16x8 vf[4][2];
#pragma unroll
    for (int nd = 0; nd < 4; nd++) {
      vf[nd][0] = *(const bf16x8*)&Vs[cur][nd * 1024 + lofs];
      vf[nd][1] = *(const bf16x8*)&Vs[cur][nd * 1024 + 512 + lofs];
    }
#pragma unroll
    for (int s = 0; s < 4; s++) {
      bf16x8 ap0 = *(const bf16x8*)&Ps[w][(s * 16 + l15) * 72 + quad * 8];
      bf16x8 ap1 = *(const bf16x8*)&Ps[w][(s * 16 + l15) * 72 + 32 + quad * 8];
      lacc[s] = mfma16(ap0, vone, lacc[s]);
      lacc[s] = mfma16(ap1, vone, lacc[s]);
#pragma unroll
      for (int nd = 0; nd < 4; nd++) {
        o[s][nd] = mfma16(ap0, vf[nd][0], o[s][nd]);
        o[s][nd] = mfma16(ap1, vf[nd][1], o[s][nd]);
      }
    }
  }

  const size_t bpart = (size_t)(h * 8 + kz);
#pragma unroll
  for (int s = 0; s < 4; s++) {
#pragma unroll
    for (int nd = 0; nd < 4; nd++)
#pragma unroll
      for (int r = 0; r < 4; r++) {
        int row = qbase + w * 64 + s * 16 + quad * 4 + r;
        Opart[(bpart * 8192 + row) * 64 + nd * 16 + l15] = f2bf(o[s][nd][r]);
      }
    if (l15 == 0) {
#pragma unroll
      for (int r = 0; r < 4; r++) {
        int row = qbase + w * 64 + s * 16 + quad * 4 + r;
        Lpart[bpart * 8192 + row] = lacc[s][r];
      }
    }
  }
}

// -------------- fused: attn-combine + out_proj + residual + LN1 ------------
__global__ __launch_bounds__(256) void k_oproj_ln(
    const __bf16* __restrict__ Opart, const float* __restrict__ Lpart,
    const __bf16* __restrict__ Wo, const float* __restrict__ ob,
    const float* __restrict__ hf, const float* __restrict__ g,
    const float* __restrict__ bt, float* __restrict__ h1f,
    __bf16* __restrict__ h1b) {
  __shared__ __bf16 Af[4 * 2048];
  __shared__ __bf16 Bf[8 * 2048];
  __shared__ float scr1[64][2], scr2[64][2];
  const int tid = threadIdx.x, lane = tid & 63, w = tid >> 6;
  const int l15 = lane & 15, quad = lane >> 4;
  const int lofs = lane * 8;
  const int bm = blockIdx.x * 64;
  const int wm = w & 1, wn = w >> 1;

#pragma unroll
  for (int f = 0; f < 2; f++) {
    int j = w * 2 + f;
#pragma unroll
    for (int kq = 0; kq < 4; kq++)
      GLD16(Wo + (size_t)(j * 16 + l15) * 128 + kq * 32 + quad * 8,
            &Bf[j * 2048 + kq * 512]);
  }
  {
    int n = bm + w * 16 + l15;
    float L0 = 0.f, L1 = 0.f;
#pragma unroll
    for (int z = 0; z < 8; z++) {
      L0 += Lpart[(size_t)z * 8192 + n];
      L1 += Lpart[(size_t)(8 + z) * 8192 + n];
    }
    float r0 = 1.f / L0, r1 = 1.f / L1;
#pragma unroll
    for (int kq = 0; kq < 4; kq++) {
      int hh = kq >> 1;
      int d0 = (kq & 1) * 32 + quad * 8;
      float acc8[8] = {};
#pragma unroll
      for (int z = 0; z < 8; z++) {
        bf16x8 t = *(const bf16x8*)&Opart[((size_t)(hh * 8 + z) * 8192 + n) *
                                              64 + d0];
        float f[8];
        ub8(t, f);
#pragma unroll
        for (int e = 0; e < 8; e++) acc8[e] += f[e];
      }
      float rh = hh ? r1 : r0;
      union { unsigned short s[8]; bf16x8 v; } u;
#pragma unroll
      for (int e = 0; e < 8; e++) u.s[e] = f2bf_bits(acc8[e] * rh);
      *(bf16x8*)&Af[w * 2048 + kq * 512 + lane * 8] = u.v;
    }
  }
  __syncthreads();

  f32x4 acc[2][4] = {};
#pragma unroll
  for (int kq = 0; kq < 4; kq++) {
    bf16x8 a[2], b[4];
#pragma unroll
    for (int mt = 0; mt < 2; mt++)
      a[mt] = *(const bf16x8*)&Af[(wm * 2 + mt) * 2048 + kq * 512 + lofs];
#pragma unroll
    for (int nt = 0; nt < 4; nt++)
      b[nt] = *(const bf16x8*)&Bf[(wn * 4 + nt) * 2048 + kq * 512 + lofs];
#pragma unroll
    for (int mt = 0; mt < 2; mt++)
#pragma unroll
      for (int nt = 0; nt < 4; nt++)
        acc[mt][nt] = mfma16(a[mt], b[nt], acc[mt][nt]);
  }

  float v[2][4][4];
#pragma unroll
  for (int mt = 0; mt < 2; mt++)
#pragma unroll
    for (int r = 0; r < 4; r++) {
      int row = bm + wm * 32 + mt * 16 + quad * 4 + r;
      float s1 = 0.f, s2 = 0.f;
#pragma unroll
      for (int nt = 0; nt < 4; nt++) {
        int col = wn * 64 + nt * 16 + l15;
        float val = acc[mt][nt][r] + ob[col] + hf[(size_t)row * 128 + col];
        v[mt][nt][r] = val;
        s1 += val;
        s2 += val * val;
      }
#pragma unroll
      for (int msk = 1; msk < 16; msk <<= 1) {
        s1 += __shfl_xor(s1, msk);
        s2 += __shfl_xor(s2, msk);
      }
      if (l15 == 0) {
        int rl = wm * 32 + mt * 16 + quad * 4 + r;
        scr1[rl][wn] = s1;
        scr2[rl][wn] = s2;
      }
    }
  __syncthreads();
#pragma unroll
  for (int mt = 0; mt < 2; mt++)
#pragma unroll
    for (int r = 0; r < 4; r++) {
      int rl = wm * 32 + mt * 16 + quad * 4 + r;
      int row = bm + rl;
      float S1 = scr1[rl][0] + scr1[rl][1];
      float S2 = scr2[rl][0] + scr2[rl][1];
      float mu = S1 * (1.f / 128.f);
      float var = S2 * (1.f / 128.f) - mu * mu;
      float rstd = rsqrtf(var + 1e-5f);
#pragma unroll
      for (int nt = 0; nt < 4; nt++) {
        int col = wn * 64 + nt * 16 + l15;
        float y = (v[mt][nt][r] - mu) * rstd * g[col] + bt[col];
        h1f[(size_t)row * 128 + col] = y;
        h1b[(size_t)row * 128 + col] = f2bf(y);
      }
    }
}

// --- fused tail: FF2-partial combine + bias + residual + LN2 + fc + head ---
__global__ __launch_bounds__(256) void k_tail(
    const float* __restrict__ h1f, const float* __restrict__ part,
    const float* __restrict__ pbias, const float* __restrict__ g,
    const float* __restrict__ bt, const __bf16* __restrict__ Wfc,
    const float* __restrict__ fcb, const float* __restrict__ hw,
    const float* __restrict__ hb, float* __restrict__ out) {
  __shared__ __bf16 Af[2 * 2048];
  __shared__ __bf16 Bf[16 * 2048];
  __shared__ float scr0[32][4], scr1[32][4];
  const int tid = threadIdx.x, lane = tid & 63, w = tid >> 6;
  const int l15 = lane & 15, quad = lane >> 4;
  const int lofs = lane * 8;
  const int bm = blockIdx.x * 32;

  if (w >= 2) {
#pragma unroll
    for (int f = 0; f < 8; f++) {
      int j = (w - 2) * 8 + f;
#pragma unroll
      for (int kq = 0; kq < 4; kq++)
        GLD16(Wfc + (size_t)(j * 16 + l15) * 128 + kq * 32 + quad * 8,
              &Bf[j * 2048 + kq * 512]);
    }
  } else {
    int row = bm + w * 16 + l15;
    float val[4][8];
    float s1 = 0.f, s2 = 0.f;
#pragma unroll
    for (int kq = 0; kq < 4; kq++) {
      int c0 = kq * 32 + quad * 8;
      const float* h1p = h1f + (size_t)row * 128 + c0;
#pragma unroll
      for (int j = 0; j < 8; j++) val[kq][j] = h1p[j] + pbias[c0 + j];
#pragma unroll
      for (int z = 0; z < 8; z++) {
        const float* pp = part + (size_t)z * 1048576 + (size_t)row * 128 + c0;
#pragma unroll
        for (int j = 0; j < 8; j++) val[kq][j] += pp[j];
      }
#pragma unroll
      for (int j = 0; j < 8; j++) {
        s1 += val[kq][j];
        s2 += val[kq][j] * val[kq][j];
      }
    }
    s1 += __shfl_xor(s1, 16); s1 += __shfl_xor(s1, 32);
    s2 += __shfl_xor(s2, 16); s2 += __shfl_xor(s2, 32);
    float mu = s1 * (1.f / 128.f);
    float var = s2 * (1.f / 128.f) - mu * mu;
    float rstd = rsqrtf(var + 1e-5f);
#pragma unroll
    for (int kq = 0; kq < 4; kq++) {
      int c0 = kq * 32 + quad * 8;
      union { unsigned short s[8]; bf16x8 v; } u;
#pragma unroll
      for (int j = 0; j < 8; j++)
        u.s[j] = f2bf_bits((val[kq][j] - mu) * rstd * g[c0 + j] + bt[c0 + j]);
      *(bf16x8*)&Af[w * 2048 + kq * 512 + lane * 8] = u.v;
    }
  }
  __syncthreads();

  f32x4 acc[2][4] = {};
#pragma unroll
  for (int kq = 0; kq < 4; kq++) {
    bf16x8 a[2], b[4];
#pragma unroll
    for (int mt = 0; mt < 2; mt++)
      a[mt] = *(const bf16x8*)&Af[mt * 2048 + kq * 512 + lofs];
#pragma unroll
    for (int nt = 0; nt < 4; nt++)
      b[nt] = *(const bf16x8*)&Bf[(w * 4 + nt) * 2048 + kq * 512 + lofs];
#pragma unroll
    for (int mt = 0; mt < 2; mt++)
#pragma unroll
      for (int nt = 0; nt < 4; nt++)
        acc[mt][nt] = mfma16(a[mt], b[nt], acc[mt][nt]);
  }

#pragma unroll
  for (int mt = 0; mt < 2; mt++)
#pragma unroll
    for (int r = 0; r < 4; r++) {
      float p0 = 0.f, p1 = 0.f;
#pragma unroll
      for (int nt = 0; nt < 4; nt++) {
        int col = w * 64 + nt * 16 + l15;
        float vv = fmaxf(acc[mt][nt][r] + fcb[col], 0.f);
        p0 += vv * hw[col];
        p1 += vv * hw[256 + col];
      }
#pragma unroll
      for (int msk = 1; msk < 16; msk <<= 1) {
        p0 += __shfl_xor(p0, msk);
        p1 += __shfl_xor(p1, msk);
      }
      if (l15 == 0) {
        int rl = mt * 16 + quad * 4 + r;
        scr0[rl][w] = p0;
        scr1[rl][w] = p1;
      }
    }
  __syncthreads();
  if (tid < 32) {
    float p0 = scr0[tid][0] + scr0[tid][1] + scr0[tid][2] + scr0[tid][3];
    float p1 = scr1[tid][0] + scr1[tid][1] + scr1[tid][2] + scr1[tid][3];
    out[(size_t)(bm + tid) * 2]     = p0 + hb[0];
    out[(size_t)(bm + tid) * 2 + 1] = p1 + hb[1];
  }
}

// ------------------------------ launcher -----------------------------------
extern "C" void kernel_launch(void* const* d_in, const int* in_sizes, int n_in,
                              void* d_out, int out_size, void* d_ws,
                              size_t ws_size, hipStream_t stream) {
  const float* x     = (const float*)d_in[0];
  const int*   ei    = (const int*)d_in[1];
  const float* beta  = (const float*)d_in[2];
  const float* in_w  = (const float*)d_in[3];
  const float* in_b  = (const float*)d_in[4];
  const float* out_w = (const float*)d_in[5];
  const float* out_b = (const float*)d_in[6];
  const float* ln1g  = (const float*)d_in[7];
  const float* ln1b  = (const float*)d_in[8];
  const float* ff1w  = (const float*)d_in[9];
  const float* ff1b  = (const float*)d_in[10];
  const float* ff2w  = (const float*)d_in[11];
  const float* ff2b  = (const float*)d_in[12];
  const float* ln2g  = (const float*)d_in[13];
  const float* ln2b  = (const float*)d_in[14];
  const float* fcw   = (const float*)d_in[15];
  const float* fcb   = (const float*)d_in[16];
  const float* hw    = (const float*)d_in[17];
  const float* hbias = (const float*)d_in[18];
  float* out = (float*)d_out;
  const int N = 8192;
  const int E = in_sizes[1] / 2;

  char* wsp = (char*)d_ws;
  size_t off = 0;
  auto alloc = [&](size_t b) -> void* {
    void* p = wsp + off;
    off = (off + b + 255) & ~(size_t)255;
    return p;
  };

  float*  inv     = (float*)alloc((size_t)N * 4);
  int*    counts  = (int*)alloc((size_t)N * 4);
  int*    offs    = (int*)alloc((size_t)(N + 1) * 4);
  int*    cursor  = (int*)alloc((size_t)N * 4);
  int*    csr     = (int*)alloc((size_t)E * 4);
  float*  h_f     = (float*)alloc((size_t)N * 128 * 4);
  __bf16* h_b     = (__bf16*)alloc((size_t)N * 128 * 2);
  float*  h1_f    = (float*)alloc((size_t)N * 128 * 4);
  __bf16* h1_b    = (__bf16*)alloc((size_t)N * 128 * 2);
  float*  Lpart   = (float*)alloc((size_t)16 * N * 4);
  __bf16* w_in    = (__bf16*)alloc((size_t)384 * 128 * 2);
  __bf16* w_out   = (__bf16*)alloc((size_t)128 * 128 * 2);
  __bf16* w_ff1   = (__bf16*)alloc((size_t)2048 * 128 * 2);
  __bf16* w_ff2   = (__bf16*)alloc((size_t)128 * 2048 * 2);
  __bf16* w_fc    = (__bf16*)alloc((size_t)256 * 128 * 2);
  // bigA: Opart bf16 (attn, 16.7MB) aliases ff1o (33.5MB)
  char*   bigA    = (char*)alloc((size_t)16 * N * 64 * 4);
  __bf16* Opart   = (__bf16*)bigA;
  __bf16* ff1o    = (__bf16*)bigA;
  // bigB: Qb(2M)+Kb(2M)+Vtb(2M) aliases ff2part (8 x 4.2MB = 33.6MB)
  char*   bigB    = (char*)alloc((size_t)33554432);
  __bf16* Qb      = (__bf16*)bigB;
  __bf16* Kb      = (__bf16*)(bigB + 2097152);
  __bf16* Vtb     = (__bf16*)(bigB + 2 * 2097152);
  float*  ff2part = (float*)bigB;
  (void)ws_size; (void)n_in; (void)out_size;

  k_prep<<<4784, 256, 0, stream>>>(x, inv, counts, in_w, out_w, ff1w, ff2w,
                                   fcw, w_in, w_out, w_ff1, w_ff2, w_fc);
  k_count<<<(E + 255) / 256, 256, 0, stream>>>(ei, counts, E);
  k_scan<<<1, 256, 0, stream>>>(counts, offs, cursor);
  k_scatter<<<(E + 255) / 256, 256, 0, stream>>>(ei, cursor, csr, E);
  k_agnn<<<N / 4, 256, 0, stream>>>(x, csr, offs, inv, beta, h_f, h_b);

  k_gemm_qkv<<<dim3(64, 3), 256, 0, stream>>>(h_b, w_in, in_b, Qb, Kb, Vtb);
  k_attn<<<dim3(32, 2, 8), 256, 0, stream>>>(Qb, Kb, Vtb, Opart, Lpart);
  k_oproj_ln<<<128, 256, 0, stream>>>(Opart, Lpart, w_out, out_b, h_f, ln1g,
                                      ln1b, h1_f, h1_b);
  // FF1 (relu, bf16)  -- writes ff1o (bigA; Opart now dead)
  k_gemm<<<dim3(64, 16, 1), 256, 0, stream>>>(h1_b, w_ff1, ff1b, nullptr, ff1o,
                                              nullptr, N, 2048, 128, 1);
  // FF2 split-K=8 -> ff2part (bigB; Qb/Kb/Vtb now dead)
  k_gemm<<<dim3(64, 1, 8), 256, 0, stream>>>(ff1o, w_ff2, nullptr, nullptr,
                                             nullptr, ff2part, N, 128, 2048, 0);
  // FF2 combine + LN2 + fc(relu) + head
  k_tail<<<256, 256, 0, stream>>>(h1_f, ff2part, ff2b, ln2g, ln2b, w_fc, fcb,
                                  hw, hbias, out);
}

// Round 14
// 261.215 us; speedup vs baseline: 1.0079x; 1.0079x over previous
//
#include <hip/hip_runtime.h>

// ---------------------------------------------------------------------------
// RestaurantGNN: AGNNConv -> TransformerEncoderLayer (post-LN) -> fc -> head
// N=8192, D=128, NH=2, HD=64, DFF=2048, H=256, E=262144
// Round 14: k_attn reverted to R12 (single-buffer; dbuf was neutral per R13,
// matching m99/m100). FF2 split-K partials stored bf16 (33.6 -> 16.8 MB each
// way); k_tail reads bf16 partials. Everything else R12-proven.
// ---------------------------------------------------------------------------

typedef __attribute__((ext_vector_type(4))) float  f32x4;
typedef __attribute__((ext_vector_type(8))) __bf16 bf16x8;

#define DEV __device__ __forceinline__

DEV unsigned short f2bf_bits(float f) {       // RNE fp32 -> bf16 bits
  union { float f; unsigned u; } v; v.f = f;
  unsigned r = v.u + 0x7FFFu + ((v.u >> 16) & 1u);
  return (unsigned short)(r >> 16);
}

DEV __bf16 f2bf(float f) {
  union { unsigned short s; __bf16 b; } o; o.s = f2bf_bits(f);
  return o.b;
}

DEV f32x4 mfma16(bf16x8 a, bf16x8 b, f32x4 c) {
  return __builtin_amdgcn_mfma_f32_16x16x32_bf16(a, b, c, 0, 0, 0);
}

DEV bf16x8 ones8() {                          // bf16 1.0 x8
  union { unsigned short s[8]; bf16x8 v; } u;
#pragma unroll
  for (int i = 0; i < 8; i++) u.s[i] = 0x3F80;
  return u.v;
}

DEV void ub8(bf16x8 v, float* f) {            // unpack 8 bf16 -> fp32
  union { bf16x8 v; unsigned short s[8]; } u; u.v = v;
#pragma unroll
  for (int i = 0; i < 8; i++) {
    union { unsigned u; float f; } w; w.u = (unsigned)u.s[i] << 16;
    f[i] = w.f;
  }
}

// async global->LDS, 16B/lane; LDS dest = wave-uniform base + lane*16
#define GLD16(gp, lp) __builtin_amdgcn_global_load_lds(                        \
    (const __attribute__((address_space(1))) void*)(gp),                       \
    (__attribute__((address_space(3))) void*)(lp), 16, 0, 0)

// --------------------- prep: norm + counts-zero + weight cvt ---------------

__global__ __launch_bounds__(256) void k_prep(
    const float* __restrict__ x, float* __restrict__ inv,
    int* __restrict__ counts, const float* __restrict__ s0,
    const float* __restrict__ s1, const float* __restrict__ s2,
    const float* __restrict__ s3, const float* __restrict__ s4, __bf16* d0,
    __bf16* d1, __bf16* d2, __bf16* d3, __bf16* d4) {
  const int n0 = 384 * 128, n1 = 128 * 128, n2 = 2048 * 128, n3 = 128 * 2048,
            n4 = 256 * 128;
  if (blockIdx.x < 2048) {
    int lane = threadIdx.x & 63, w = threadIdx.x >> 6;
    int row = blockIdx.x * 4 + w;
    float2 v = ((const float2*)(x + (size_t)row * 128))[lane];
    float s = v.x * v.x + v.y * v.y;
#pragma unroll
    for (int m = 1; m < 64; m <<= 1) s += __shfl_xor(s, m);
    if (lane == 0) {
      inv[row] = 1.f / fmaxf(sqrtf(s), 1e-12f);
      counts[row] = 0;
    }
    return;
  }
  int t = (blockIdx.x - 2048) * 256 + threadIdx.x;
  if (t < n0) { d0[t] = f2bf(s0[t]); return; } t -= n0;
  if (t < n1) { d1[t] = f2bf(s1[t]); return; } t -= n1;
  if (t < n2) { d2[t] = f2bf(s2[t]); return; } t -= n2;
  if (t < n3) { d3[t] = f2bf(s3[t]); return; } t -= n3;
  if (t < n4) { d4[t] = f2bf(s4[t]); }
}

// ------------------------------ CSR build ----------------------------------

__global__ void k_count(const int* __restrict__ ei, int* __restrict__ counts,
                        int E) {
  int e = blockIdx.x * 256 + threadIdx.x;
  if (e < E) atomicAdd(&counts[ei[E + e]], 1);
}

__global__ __launch_bounds__(256) void k_scan(const int* __restrict__ counts,
                                              int* __restrict__ offs,
                                              int* __restrict__ cursor) {
  __shared__ int sums[256];
  int t = threadIdx.x, base = t * 32;
  int s = 0;
  for (int i = 0; i < 32; i++) s += counts[base + i];
  sums[t] = s;
  __syncthreads();
  for (int off = 1; off < 256; off <<= 1) {
    int v = (t >= off) ? sums[t - off] : 0;
    __syncthreads();
    sums[t] += v;
    __syncthreads();
  }
  int run = sums[t] - s;  // exclusive prefix
  for (int i = 0; i < 32; i++) {
    offs[base + i] = run; cursor[base + i] = run;
    run += counts[base + i];
  }
  if (t == 255) offs[8192] = run;
}

__global__ void k_scatter(const int* __restrict__ ei, int* __restrict__ cursor,
                          int* __restrict__ csr, int E) {
  int e = blockIdx.x * 256 + threadIdx.x;
  if (e < E) {
    int dst = ei[E + e];
    int pos = atomicAdd(&cursor[dst], 1);
    csr[pos] = ei[e];
  }
}

// AGNN aggregate: wave per destination node, 2-edge unroll for latency ILP.
__global__ __launch_bounds__(256) void k_agnn(
    const float* __restrict__ x, const int* __restrict__ csr,
    const int* __restrict__ offs, const float* __restrict__ inv,
    const float* __restrict__ betap, float* __restrict__ hf,
    __bf16* __restrict__ hb) {
  int lane = threadIdx.x & 63, w = threadIdx.x >> 6;
  int dst = blockIdx.x * 4 + w;
  float beta = *betap;
  float2 xd = ((const float2*)(x + (size_t)dst * 128))[lane];
  float invd = inv[dst];
  float sd = xd.x * xd.x + xd.y * xd.y;
#pragma unroll
  for (int m = 1; m < 64; m <<= 1) sd += __shfl_xor(sd, m);
  float z = __expf(beta * sd * invd * invd);  // self-loop (cos==1)
  float ax = z * xd.x, ay = z * xd.y;
  int e0 = offs[dst], e1 = offs[dst + 1];
  int e = e0;
  for (; e + 2 <= e1; e += 2) {
    int s0 = csr[e], s1 = csr[e + 1];
    float2 xa = ((const float2*)(x + (size_t)s0 * 128))[lane];
    float2 xb = ((const float2*)(x + (size_t)s1 * 128))[lane];
    float ia = inv[s0], ib = inv[s1];
    float da = xd.x * xa.x + xd.y * xa.y;
    float db = xd.x * xb.x + xd.y * xb.y;
#pragma unroll
    for (int m = 1; m < 64; m <<= 1) {
      da += __shfl_xor(da, m);
      db += __shfl_xor(db, m);
    }
    float sa = __expf(beta * da * invd * ia);
    float sb = __expf(beta * db * invd * ib);
    z += sa + sb;
    ax += sa * xa.x + sb * xb.x;
    ay += sa * xa.y + sb * xb.y;
  }
  if (e < e1) {
    int s0 = csr[e];
    float2 xa = ((const float2*)(x + (size_t)s0 * 128))[lane];
    float da = xd.x * xa.x + xd.y * xa.y;
#pragma unroll
    for (int m = 1; m < 64; m <<= 1) da += __shfl_xor(da, m);
    float sa = __expf(beta * da * invd * inv[s0]);
    z += sa; ax += sa * xa.x; ay += sa * xa.y;
  }
  float r = 1.f / z;
  ax *= r; ay *= r;
  float2 o; o.x = ax; o.y = ay;
  ((float2*)(hf + (size_t)dst * 128))[lane] = o;
  hb[(size_t)dst * 128 + 2 * lane]     = f2bf(ax);
  hb[(size_t)dst * 128 + 2 * lane + 1] = f2bf(ay);
}

// ------------------------------- GEMM --------------------------------------
// C[M,N] = A[M,K] @ B[N,K]^T (+bias, optional relu). A,B bf16, fp32 acc.
// FF1: Cb bf16 output. FF2: split-K bf16 partials (Cpartb).
__global__ __launch_bounds__(256, 3) void k_gemm(
    const __bf16* __restrict__ A, const __bf16* __restrict__ B,
    const float* __restrict__ bias, float* __restrict__ Cf,
    __bf16* __restrict__ Cb, __bf16* __restrict__ Cpartb, int M, int N, int K,
    int relu) {
  __shared__ __bf16 As[128 * 64];
  __shared__ __bf16 Bs[128 * 64];
  const int tid = threadIdx.x, lane = tid & 63, wid = tid >> 6;
  const int wm = wid & 1, wn = wid >> 1;
  const int bm = blockIdx.x * 128, bn = blockIdx.y * 128;
  const int kz = blockIdx.z, nkz = gridDim.z;
  const int kchunk = K / nkz, k0beg = kz * kchunk, k0end = k0beg + kchunk;
  const int lr = lane >> 3, lc8 = (lane & 7) * 8;
  const int l15 = lane & 15, quad = lane >> 4, kq = quad * 8;

  f32x4 acc[4][4] = {};
  const __bf16* Ab = A + (size_t)(bm + lr) * K + lc8;
  const __bf16* Bb = B + (size_t)(bn + lr) * K + lc8;

  for (int k0 = k0beg; k0 < k0end; k0 += 64) {
#pragma unroll
    for (int i = 0; i < 4; i++) {
      int j = wid * 4 + i;
      GLD16(Ab + (size_t)(8 * j) * K + k0, &As[j * 512]);
      GLD16(Bb + (size_t)(8 * j) * K + k0, &Bs[j * 512]);
    }
    __syncthreads();
    const int ar = (wm * 64 + l15) * 64 + kq;
    const int br = (wn * 64 + l15) * 64 + kq;
#pragma unroll
    for (int kk = 0; kk < 2; kk++) {
      bf16x8 a[4], b[4];
#pragma unroll
      for (int mt = 0; mt < 4; mt++)
        a[mt] = *(const bf16x8*)&As[ar + mt * 1024 + kk * 32];
#pragma unroll
      for (int nt = 0; nt < 4; nt++)
        b[nt] = *(const bf16x8*)&Bs[br + nt * 1024 + kk * 32];
#pragma unroll
      for (int mt = 0; mt < 4; mt++)
#pragma unroll
        for (int nt = 0; nt < 4; nt++)
          acc[mt][nt] = mfma16(a[mt], b[nt], acc[mt][nt]);
    }
    __syncthreads();
  }
  const int col0 = bn + wn * 64 + l15;
  const int row0 = bm + wm * 64 + quad * 4;
  if (Cpartb) {
    __bf16* P = Cpartb + (size_t)kz * M * N;
#pragma unroll
    for (int mt = 0; mt < 4; mt++)
#pragma unroll
      for (int nt = 0; nt < 4; nt++)
#pragma unroll
        for (int r = 0; r < 4; r++)
          P[(size_t)(row0 + mt * 16 + r) * N + col0 + nt * 16] =
              f2bf(acc[mt][nt][r]);
  } else {
#pragma unroll
    for (int nt = 0; nt < 4; nt++) {
      float bv = bias[col0 + nt * 16];
#pragma unroll
      for (int mt = 0; mt < 4; mt++)
#pragma unroll
        for (int r = 0; r < 4; r++) {
          float v = acc[mt][nt][r] + bv;
          if (relu) v = fmaxf(v, 0.f);
          size_t idx = (size_t)(row0 + mt * 16 + r) * N + col0 + nt * 16;
          if (Cf) Cf[idx] = v;
          if (Cb) Cb[idx] = f2bf(v);
        }
    }
  }
}

// ------------------- qkv GEMM with fused Q/K/V epilogue --------------------
__global__ __launch_bounds__(256, 2) void k_gemm_qkv(
    const __bf16* __restrict__ A, const __bf16* __restrict__ B,
    const float* __restrict__ bias, __bf16* __restrict__ Qb,
    __bf16* __restrict__ Kb, __bf16* __restrict__ Vtb) {
  __shared__ __bf16 smem[17408];  // staging 2x8192 | transpose tile 128x136
  __bf16* As = smem;
  __bf16* Bs = smem + 8192;
  const int K = 128;
  const int tid = threadIdx.x, lane = tid & 63, wid = tid >> 6;
  const int wm = wid & 1, wn = wid >> 1;
  const int bm = blockIdx.x * 128, y = blockIdx.y, bn = y * 128;
  const int lr = lane >> 3, lc8 = (lane & 7) * 8;
  const int l15 = lane & 15, quad = lane >> 4, kq = quad * 8;
  const float qscale = 0.125f * 1.44269504089f;

  f32x4 acc[4][4] = {};
  const __bf16* Ab = A + (size_t)(bm + lr) * K + lc8;
  const __bf16* Bb = B + (size_t)(bn + lr) * K + lc8;

  for (int k0 = 0; k0 < 128; k0 += 64) {
#pragma unroll
    for (int i = 0; i < 4; i++) {
      int j = wid * 4 + i;
      GLD16(Ab + (size_t)(8 * j) * K + k0, &As[j * 512]);
      GLD16(Bb + (size_t)(8 * j) * K + k0, &Bs[j * 512]);
    }
    __syncthreads();
    const int ar = (wm * 64 + l15) * 64 + kq;
    const int br = (wn * 64 + l15) * 64 + kq;
#pragma unroll
    for (int kk = 0; kk < 2; kk++) {
      bf16x8 a[4], b[4];
#pragma unroll
      for (int mt = 0; mt < 4; mt++)
        a[mt] = *(const bf16x8*)&As[ar + mt * 1024 + kk * 32];
#pragma unroll
      for (int nt = 0; nt < 4; nt++)
        b[nt] = *(const bf16x8*)&Bs[br + nt * 1024 + kk * 32];
#pragma unroll
      for (int mt = 0; mt < 4; mt++)
#pragma unroll
        for (int nt = 0; nt < 4; nt++)
          acc[mt][nt] = mfma16(a[mt], b[nt], acc[mt][nt]);
    }
    __syncthreads();
  }

  if (y < 2) {
    __bf16* D = (y == 0) ? Qb : Kb;
    float sc = (y == 0) ? qscale : 1.f;
    int h = wn;
#pragma unroll
    for (int nt = 0; nt < 4; nt++) {
      int c = wn * 64 + nt * 16 + l15;
      float bv = bias[bn + c];
      int d = nt * 16 + l15;
#pragma unroll
      for (int mt = 0; mt < 4; mt++)
#pragma unroll
        for (int r = 0; r < 4; r++) {
          int row = bm + wm * 64 + mt * 16 + quad * 4 + r;
          D[(size_t)h * 524288 + (size_t)row * 64 + d] =
              f2bf((acc[mt][nt][r] + bv) * sc);
        }
    }
  } else {
#pragma unroll
    for (int nt = 0; nt < 4; nt++) {
      int c = wn * 64 + nt * 16 + l15;
      float bv = bias[bn + c];
#pragma unroll
      for (int mt = 0; mt < 4; mt++)
#pragma unroll
        for (int r = 0; r < 4; r++) {
          int nl = wm * 64 + mt * 16 + quad * 4 + r;
          smem[nl * 136 + c] = f2bf(acc[mt][nt][r] + bv);
        }
    }
    __syncthreads();
    int d = tid >> 1, nh = tid & 1;
    __bf16* dst = Vtb + (size_t)d * 8192 + bm + nh * 64;
#pragma unroll
    for (int i = 0; i < 8; i++) {
      union { unsigned short s[8]; bf16x8 v; } u;
#pragma unroll
      for (int e = 0; e < 8; e++)
        u.s[e] = *(const unsigned short*)&smem[(nh * 64 + i * 8 + e) * 136 + d];
      *(bf16x8*)(dst + i * 8) = u.v;
    }
  }
}

// ------------------------- flash attention ---------------------------------
// R12-proven: 256 thr (4 waves); wave = 64 q (4 subtiles); K-split=8;
// single-buffered (dbuf neutral per R13); Ps stride 72; bounds(256,2)
// -> 112 VGPR no-spill.
__global__ __launch_bounds__(256, 2) void k_attn(
    const __bf16* __restrict__ Qb, const __bf16* __restrict__ Kb,
    const __bf16* __restrict__ Vtb, __bf16* __restrict__ Opart,
    float* __restrict__ Lpart) {
  __shared__ __bf16 Ks[4096];        // 4 frag x 2 khalf x 512
  __shared__ __bf16 Vs[4096];
  __shared__ __bf16 Ps[4][64 * 72];  // per-wave P [q_local 64][k], stride 72

  const int tid = threadIdx.x, lane = tid & 63, w = tid >> 6;
  const int qt = blockIdx.x, h = blockIdx.y, kz = blockIdx.z;
  const int qbase = qt * 256;
  const int l15 = lane & 15, quad = lane >> 4;
  const int lofs = lane * 8;

  const __bf16* Qg = Qb + ((size_t)h * 8192 + qbase) * 64;
  const __bf16* Kg = Kb + (size_t)h * 8192 * 64;
  const __bf16* Vg = Vtb + (size_t)h * 64 * 8192;
  const bf16x8 vone = ones8();

  // stage Q (256 q x 64 d = 32KB) fragment-major into the Ps region
  __bf16* Qstage = &Ps[0][0];
#pragma unroll
  for (int i = 0; i < 4; i++) {
    int j = w * 4 + i;  // 16 frags of 16 q-rows
#pragma unroll
    for (int hh = 0; hh < 2; hh++)
      GLD16(Qg + (size_t)(j * 16 + l15) * 64 + hh * 32 + quad * 8,
            Qstage + j * 1024 + hh * 512);
  }
  __syncthreads();
  bf16x8 aq[4][2];
#pragma unroll
  for (int s = 0; s < 4; s++) {
    const __bf16* base = Qstage + (size_t)(w * 4 + s) * 1024;
    aq[s][0] = *(const bf16x8*)&base[lofs];
    aq[s][1] = *(const bf16x8*)&base[512 + lofs];
  }
  __syncthreads();

  f32x4 o[4][4] = {};
  f32x4 lacc[4] = {};
  const int kstart = kz * 1024;

  for (int kt = 0; kt < 16; kt++) {
    int kb = kstart + kt * 64;
#pragma unroll
    for (int hh = 0; hh < 2; hh++) {
      GLD16(Kg + (size_t)(kb + w * 16 + l15) * 64 + hh * 32 + quad * 8,
            &Ks[w * 1024 + hh * 512]);
      GLD16(Vg + (size_t)(w * 16 + l15) * 8192 + kb + hh * 32 + quad * 8,
            &Vs[w * 1024 + hh * 512]);
    }
    __syncthreads();

    // S^T = K x Q^T ; lane -> (k = mt*16+quad*4+r, q = s*16+l15)
#pragma unroll
    for (int mt = 0; mt < 4; mt++) {
      bf16x8 k0 = *(const bf16x8*)&Ks[mt * 1024 + lofs];
      bf16x8 k1 = *(const bf16x8*)&Ks[mt * 1024 + 512 + lofs];
#pragma unroll
      for (int s = 0; s < 4; s++) {
        f32x4 St = {};
        St = mfma16(k0, aq[s][0], St);
        St = mfma16(k1, aq[s][1], St);
        union { float f; unsigned u; } p0, p1, p2, p3;
        p0.f = __builtin_amdgcn_exp2f(St[0]);
        p1.f = __builtin_amdgcn_exp2f(St[1]);
        p2.f = __builtin_amdgcn_exp2f(St[2]);
        p3.f = __builtin_amdgcn_exp2f(St[3]);
        uint2 pk;
        pk.x = (p0.u >> 16) | (p1.u & 0xFFFF0000u);
        pk.y = (p2.u >> 16) | (p3.u & 0xFFFF0000u);
        *(uint2*)&Ps[w][(s * 16 + l15) * 72 + mt * 16 + quad * 4] = pk;
      }
    }
    // O += P x V ; L += P x ones   (V frags shared by all 4 subtiles)
    bf16x8 vf[4][2];
#pragma unroll
    for (int nd = 0; nd < 4; nd++) {
      vf[nd][0] = *(const bf16x8*)&Vs[nd * 1024 + lofs];
      vf[nd][1] = *(const bf16x8*)&Vs[nd * 1024 + 512 + lofs];
    }
#pragma unroll
    for (int s = 0; s < 4; s++) {
      bf16x8 ap0 = *(const bf16x8*)&Ps[w][(s * 16 + l15) * 72 + quad * 8];
      bf16x8 ap1 = *(const bf16x8*)&Ps[w][(s * 16 + l15) * 72 + 32 + quad * 8];
      lacc[s] = mfma16(ap0, vone, lacc[s]);
      lacc[s] = mfma16(ap1, vone, lacc[s]);
#pragma unroll
      for (int nd = 0; nd < 4; nd++) {
        o[s][nd] = mfma16(ap0, vf[nd][0], o[s][nd]);
        o[s][nd] = mfma16(ap1, vf[nd][1], o[s][nd]);
      }
    }
    __syncthreads();
  }

  const size_t bpart = (size_t)(h * 8 + kz);
#pragma unroll
  for (int s = 0; s < 4; s++) {
#pragma unroll
    for (int nd = 0; nd < 4; nd++)
#pragma unroll
      for (int r = 0; r < 4; r++) {
        int row = qbase + w * 64 + s * 16 + quad * 4 + r;
        Opart[(bpart * 8192 + row) * 64 + nd * 16 + l15] = f2bf(o[s][nd][r]);
      }
    if (l15 == 0) {
#pragma unroll
      for (int r = 0; r < 4; r++) {
        int row = qbase + w * 64 + s * 16 + quad * 4 + r;
        Lpart[bpart * 8192 + row] = lacc[s][r];
      }
    }
  }
}

// -------------- fused: attn-combine + out_proj + residual + LN1 ------------
__global__ __launch_bounds__(256) void k_oproj_ln(
    const __bf16* __restrict__ Opart, const float* __restrict__ Lpart,
    const __bf16* __restrict__ Wo, const float* __restrict__ ob,
    const float* __restrict__ hf, const float* __restrict__ g,
    const float* __restrict__ bt, float* __restrict__ h1f,
    __bf16* __restrict__ h1b) {
  __shared__ __bf16 Af[4 * 2048];
  __shared__ __bf16 Bf[8 * 2048];
  __shared__ float scr1[64][2], scr2[64][2];
  const int tid = threadIdx.x, lane = tid & 63, w = tid >> 6;
  const int l15 = lane & 15, quad = lane >> 4;
  const int lofs = lane * 8;
  const int bm = blockIdx.x * 64;
  const int wm = w & 1, wn = w >> 1;

#pragma unroll
  for (int f = 0; f < 2; f++) {
    int j = w * 2 + f;
#pragma unroll
    for (int kq = 0; kq < 4; kq++)
      GLD16(Wo + (size_t)(j * 16 + l15) * 128 + kq * 32 + quad * 8,
            &Bf[j * 2048 + kq * 512]);
  }
  {
    int n = bm + w * 16 + l15;
    float L0 = 0.f, L1 = 0.f;
#pragma unroll
    for (int z = 0; z < 8; z++) {
      L0 += Lpart[(size_t)z * 8192 + n];
      L1 += Lpart[(size_t)(8 + z) * 8192 + n];
    }
    float r0 = 1.f / L0, r1 = 1.f / L1;
#pragma unroll
    for (int kq = 0; kq < 4; kq++) {
      int hh = kq >> 1;
      int d0 = (kq & 1) * 32 + quad * 8;
      float acc8[8] = {};
#pragma unroll
      for (int z = 0; z < 8; z++) {
        bf16x8 t = *(const bf16x8*)&Opart[((size_t)(hh * 8 + z) * 8192 + n) *
                                              64 + d0];
        float f[8];
        ub8(t, f);
#pragma unroll
        for (int e = 0; e < 8; e++) acc8[e] += f[e];
      }
      float rh = hh ? r1 : r0;
      union { unsigned short s[8]; bf16x8 v; } u;
#pragma unroll
      for (int e = 0; e < 8; e++) u.s[e] = f2bf_bits(acc8[e] * rh);
      *(bf16x8*)&Af[w * 2048 + kq * 512 + lane * 8] = u.v;
    }
  }
  __syncthreads();

  f32x4 acc[2][4] = {};
#pragma unroll
  for (int kq = 0; kq < 4; kq++) {
    bf16x8 a[2], b[4];
#pragma unroll
    for (int mt = 0; mt < 2; mt++)
      a[mt] = *(const bf16x8*)&Af[(wm * 2 + mt) * 2048 + kq * 512 + lofs];
#pragma unroll
    for (int nt = 0; nt < 4; nt++)
      b[nt] = *(const bf16x8*)&Bf[(wn * 4 + nt) * 2048 + kq * 512 + lofs];
#pragma unroll
    for (int mt = 0; mt < 2; mt++)
#pragma unroll
      for (int nt = 0; nt < 4; nt++)
        acc[mt][nt] = mfma16(a[mt], b[nt], acc[mt][nt]);
  }

  float v[2][4][4];
#pragma unroll
  for (int mt = 0; mt < 2; mt++)
#pragma unroll
    for (int r = 0; r < 4; r++) {
      int row = bm + wm * 32 + mt * 16 + quad * 4 + r;
      float s1 = 0.f, s2 = 0.f;
#pragma unroll
      for (int nt = 0; nt < 4; nt++) {
        int col = wn * 64 + nt * 16 + l15;
        float val = acc[mt][nt][r] + ob[col] + hf[(size_t)row * 128 + col];
        v[mt][nt][r] = val;
        s1 += val;
        s2 += val * val;
      }
#pragma unroll
      for (int msk = 1; msk < 16; msk <<= 1) {
        s1 += __shfl_xor(s1, msk);
        s2 += __shfl_xor(s2, msk);
      }
      if (l15 == 0) {
        int rl = wm * 32 + mt * 16 + quad * 4 + r;
        scr1[rl][wn] = s1;
        scr2[rl][wn] = s2;
      }
    }
  __syncthreads();
#pragma unroll
  for (int mt = 0; mt < 2; mt++)
#pragma unroll
    for (int r = 0; r < 4; r++) {
      int rl = wm * 32 + mt * 16 + quad * 4 + r;
      int row = bm + rl;
      float S1 = scr1[rl][0] + scr1[rl][1];
      float S2 = scr2[rl][0] + scr2[rl][1];
      float mu = S1 * (1.f / 128.f);
      float var = S2 * (1.f / 128.f) - mu * mu;
      float rstd = rsqrtf(var + 1e-5f);
#pragma unroll
      for (int nt = 0; nt < 4; nt++) {
        int col = wn * 64 + nt * 16 + l15;
        float y = (v[mt][nt][r] - mu) * rstd * g[col] + bt[col];
        h1f[(size_t)row * 128 + col] = y;
        h1b[(size_t)row * 128 + col] = f2bf(y);
      }
    }
}

// --- fused tail: FF2-partial combine + bias + residual + LN2 + fc + head ---
// grid 256 x 32 rows; sums 8 bf16 split-K partials.
__global__ __launch_bounds__(256) void k_tail(
    const float* __restrict__ h1f, const __bf16* __restrict__ part,
    const float* __restrict__ pbias, const float* __restrict__ g,
    const float* __restrict__ bt, const __bf16* __restrict__ Wfc,
    const float* __restrict__ fcb, const float* __restrict__ hw,
    const float* __restrict__ hb, float* __restrict__ out) {
  __shared__ __bf16 Af[2 * 2048];
  __shared__ __bf16 Bf[16 * 2048];
  __shared__ float scr0[32][4], scr1[32][4];
  const int tid = threadIdx.x, lane = tid & 63, w = tid >> 6;
  const int l15 = lane & 15, quad = lane >> 4;
  const int lofs = lane * 8;
  const int bm = blockIdx.x * 32;

  if (w >= 2) {
#pragma unroll
    for (int f = 0; f < 8; f++) {
      int j = (w - 2) * 8 + f;
#pragma unroll
      for (int kq = 0; kq < 4; kq++)
        GLD16(Wfc + (size_t)(j * 16 + l15) * 128 + kq * 32 + quad * 8,
              &Bf[j * 2048 + kq * 512]);
    }
  } else {
    int row = bm + w * 16 + l15;
    float val[4][8];
    float s1 = 0.f, s2 = 0.f;
#pragma unroll
    for (int kq = 0; kq < 4; kq++) {
      int c0 = kq * 32 + quad * 8;
      const float* h1p = h1f + (size_t)row * 128 + c0;
#pragma unroll
      for (int j = 0; j < 8; j++) val[kq][j] = h1p[j] + pbias[c0 + j];
#pragma unroll
      for (int z = 0; z < 8; z++) {
        bf16x8 t = *(const bf16x8*)&part[(size_t)z * 1048576 +
                                         (size_t)row * 128 + c0];
        float f[8];
        ub8(t, f);
#pragma unroll
        for (int j = 0; j < 8; j++) val[kq][j] += f[j];
      }
#pragma unroll
      for (int j = 0; j < 8; j++) {
        s1 += val[kq][j];
        s2 += val[kq][j] * val[kq][j];
      }
    }
    s1 += __shfl_xor(s1, 16); s1 += __shfl_xor(s1, 32);
    s2 += __shfl_xor(s2, 16); s2 += __shfl_xor(s2, 32);
    float mu = s1 * (1.f / 128.f);
    float var = s2 * (1.f / 128.f) - mu * mu;
    float rstd = rsqrtf(var + 1e-5f);
#pragma unroll
    for (int kq = 0; kq < 4; kq++) {
      int c0 = kq * 32 + quad * 8;
      union { unsigned short s[8]; bf16x8 v; } u;
#pragma unroll
      for (int j = 0; j < 8; j++)
        u.s[j] = f2bf_bits((val[kq][j] - mu) * rstd * g[c0 + j] + bt[c0 + j]);
      *(bf16x8*)&Af[w * 2048 + kq * 512 + lane * 8] = u.v;
    }
  }
  __syncthreads();

  f32x4 acc[2][4] = {};
#pragma unroll
  for (int kq = 0; kq < 4; kq++) {
    bf16x8 a[2], b[4];
#pragma unroll
    for (int mt = 0; mt < 2; mt++)
      a[mt] = *(const bf16x8*)&Af[mt * 2048 + kq * 512 + lofs];
#pragma unroll
    for (int nt = 0; nt < 4; nt++)
      b[nt] = *(const bf16x8*)&Bf[(w * 4 + nt) * 2048 + kq * 512 + lofs];
#pragma unroll
    for (int mt = 0; mt < 2; mt++)
#pragma unroll
      for (int nt = 0; nt < 4; nt++)
        acc[mt][nt] = mfma16(a[mt], b[nt], acc[mt][nt]);
  }

#pragma unroll
  for (int mt = 0; mt < 2; mt++)
#pragma unroll
    for (int r = 0; r < 4; r++) {
      float p0 = 0.f, p1 = 0.f;
#pragma unroll
      for (int nt = 0; nt < 4; nt++) {
        int col = w * 64 + nt * 16 + l15;
        float vv = fmaxf(acc[mt][nt][r] + fcb[col], 0.f);
        p0 += vv * hw[col];
        p1 += vv * hw[256 + col];
      }
#pragma unroll
      for (int msk = 1; msk < 16; msk <<= 1) {
        p0 += __shfl_xor(p0, msk);
        p1 += __shfl_xor(p1, msk);
      }
      if (l15 == 0) {
        int rl = mt * 16 + quad * 4 + r;
        scr0[rl][w] = p0;
        scr1[rl][w] = p1;
      }
    }
  __syncthreads();
  if (tid < 32) {
    float p0 = scr0[tid][0] + scr0[tid][1] + scr0[tid][2] + scr0[tid][3];
    float p1 = scr1[tid][0] + scr1[tid][1] + scr1[tid][2] + scr1[tid][3];
    out[(size_t)(bm + tid) * 2]     = p0 + hb[0];
    out[(size_t)(bm + tid) * 2 + 1] = p1 + hb[1];
  }
}

// ------------------------------ launcher -----------------------------------
extern "C" void kernel_launch(void* const* d_in, const int* in_sizes, int n_in,
                              void* d_out, int out_size, void* d_ws,
                              size_t ws_size, hipStream_t stream) {
  const float* x     = (const float*)d_in[0];
  const int*   ei    = (const int*)d_in[1];
  const float* beta  = (const float*)d_in[2];
  const float* in_w  = (const float*)d_in[3];
  const float* in_b  = (const float*)d_in[4];
  const float* out_w = (const float*)d_in[5];
  const float* out_b = (const float*)d_in[6];
  const float* ln1g  = (const float*)d_in[7];
  const float* ln1b  = (const float*)d_in[8];
  const float* ff1w  = (const float*)d_in[9];
  const float* ff1b  = (const float*)d_in[10];
  const float* ff2w  = (const float*)d_in[11];
  const float* ff2b  = (const float*)d_in[12];
  const float* ln2g  = (const float*)d_in[13];
  const float* ln2b  = (const float*)d_in[14];
  const float* fcw   = (const float*)d_in[15];
  const float* fcb   = (const float*)d_in[16];
  const float* hw    = (const float*)d_in[17];
  const float* hbias = (const float*)d_in[18];
  float* out = (float*)d_out;
  const int N = 8192;
  const int E = in_sizes[1] / 2;

  char* wsp = (char*)d_ws;
  size_t off = 0;
  auto alloc = [&](size_t b) -> void* {
    void* p = wsp + off;
    off = (off + b + 255) & ~(size_t)255;
    return p;
  };

  float*  inv     = (float*)alloc((size_t)N * 4);
  int*    counts  = (int*)alloc((size_t)N * 4);
  int*    offs    = (int*)alloc((size_t)(N + 1) * 4);
  int*    cursor  = (int*)alloc((size_t)N * 4);
  int*    csr     = (int*)alloc((size_t)E * 4);
  float*  h_f     = (float*)alloc((size_t)N * 128 * 4);
  __bf16* h_b     = (__bf16*)alloc((size_t)N * 128 * 2);
  float*  h1_f    = (float*)alloc((size_t)N * 128 * 4);
  __bf16* h1_b    = (__bf16*)alloc((size_t)N * 128 * 2);
  float*  Lpart   = (float*)alloc((size_t)16 * N * 4);
  __bf16* w_in    = (__bf16*)alloc((size_t)384 * 128 * 2);
  __bf16* w_out   = (__bf16*)alloc((size_t)128 * 128 * 2);
  __bf16* w_ff1   = (__bf16*)alloc((size_t)2048 * 128 * 2);
  __bf16* w_ff2   = (__bf16*)alloc((size_t)128 * 2048 * 2);
  __bf16* w_fc    = (__bf16*)alloc((size_t)256 * 128 * 2);
  // bigA: Opart bf16 (attn, 16.7MB) aliases ff1o (33.5MB)
  char*   bigA    = (char*)alloc((size_t)16 * N * 64 * 4);
  __bf16* Opart   = (__bf16*)bigA;
  __bf16* ff1o    = (__bf16*)bigA;
  // bigB: Qb(2M)+Kb(2M)+Vtb(2M) aliases ff2part bf16 (8 x 2.1MB = 16.8MB)
  char*   bigB    = (char*)alloc((size_t)16777216);
  __bf16* Qb      = (__bf16*)bigB;
  __bf16* Kb      = (__bf16*)(bigB + 2097152);
  __bf16* Vtb     = (__bf16*)(bigB + 2 * 2097152);
  __bf16* ff2part = (__bf16*)bigB;
  (void)ws_size; (void)n_in; (void)out_size;

  k_prep<<<4784, 256, 0, stream>>>(x, inv, counts, in_w, out_w, ff1w, ff2w,
                                   fcw, w_in, w_out, w_ff1, w_ff2, w_fc);
  k_count<<<(E + 255) / 256, 256, 0, stream>>>(ei, counts, E);
  k_scan<<<1, 256, 0, stream>>>(counts, offs, cursor);
  k_scatter<<<(E + 255) / 256, 256, 0, stream>>>(ei, cursor, csr, E);
  k_agnn<<<N / 4, 256, 0, stream>>>(x, csr, offs, inv, beta, h_f, h_b);

  k_gemm_qkv<<<dim3(64, 3), 256, 0, stream>>>(h_b, w_in, in_b, Qb, Kb, Vtb);
  k_attn<<<dim3(32, 2, 8), 256, 0, stream>>>(Qb, Kb, Vtb, Opart, Lpart);
  k_oproj_ln<<<128, 256, 0, stream>>>(Opart, Lpart, w_out, out_b, h_f, ln1g,
                                      ln1b, h1_f, h1_b);
  // FF1 (relu, bf16)  -- writes ff1o (bigA; Opart now dead)
  k_gemm<<<dim3(64, 16, 1), 256, 0, stream>>>(h1_b, w_ff1, ff1b, nullptr, ff1o,
                                              nullptr, N, 2048, 128, 1);
  // FF2 split-K=8, bf16 partials -> ff2part (bigB; Qb/Kb/Vtb now dead)
  k_gemm<<<dim3(64, 1, 8), 256, 0, stream>>>(ff1o, w_ff2, nullptr, nullptr,
                                             nullptr, ff2part, N, 128, 2048, 0);
  // FF2 combine + LN2 + fc(relu) + head
  k_tail<<<256, 256, 0, stream>>>(h1_f, ff2part, ff2b, ln2g, ln2b, w_fc, fcb,
                                  hw, hbias, out);
}